// Round 12
// baseline (306.153 us; speedup 1.0000x reference)
//
#include <hip/hip_runtime.h>

#define NB   8
#define NPT  2048
#define NF   128
#define CR   64
#define EPSI 1e-5

// ============================ kNN (top-16, 2-D, exact f32+FMA emulation of np/jax) ============================
// PROVEN (rounds 6/7/11): passes, ~105 us, VALU-issue-bound. FROZEN.
__global__ void __launch_bounds__(256) knn_kernel(const float* __restrict__ xyz,
                                                  int* __restrict__ idx16) {
  __shared__ float px[NPT], py[NPT], sxx[NPT];
  int b = blockIdx.x >> 9;
  const float* xb = xyz + b * 3 * NPT;
  for (int i = threadIdx.x; i < NPT; i += 256) {
    float x = xb[i], y = xb[NPT + i];
    px[i] = x; py[i] = y;
    sxx[i] = __fadd_rn(__fmul_rn(x, x), __fmul_rn(y, y));
  }
  __syncthreads();
  int lane = threadIdx.x & 63, wid = threadIdx.x >> 6;
  int q = ((blockIdx.x & 511) << 2) | wid;
  float qx = px[q], qy = py[q], qxx = sxx[q];
  float dc[32];
#pragma unroll 4
  for (int j = 0; j < 32; ++j) {
    int m = lane + (j << 6);
    float inner_s = __fmaf_rn(qy, py[m], __fmul_rn(qx, px[m]));
    dc[j] = __fadd_rn(__fsub_rn(qxx, __fmul_rn(2.0f, inner_s)), sxx[m]);
  }
  int keep = 0;
  for (int r = 0; r < 16; ++r) {
    float dmin = dc[0]; int jmin = 0;
#pragma unroll
    for (int j = 1; j < 32; ++j) {
      bool better = dc[j] < dmin;
      dmin = better ? dc[j] : dmin;
      jmin = better ? j : jmin;
    }
    float hd = dmin;
    int   hm = lane + (jmin << 6);
#pragma unroll
    for (int off = 1; off < 64; off <<= 1) {
      float od = __shfl_xor(hd, off);
      int   om = __shfl_xor(hm, off);
      bool take = (od < hd) || (od == hd && om < hm);
      hd = take ? od : hd;
      hm = take ? om : hm;
    }
    if (lane == r) keep = hm;
    bool own = (hm & 63) == lane;
    int jw = hm >> 6;
#pragma unroll
    for (int j = 0; j < 32; ++j)
      dc[j] = (own && j == jw) ? 1e38f : dc[j];
  }
  if (lane < 16) idx16[((b * NPT + q) << 4) + lane] = keep;
}

// ===================== generic conv + atomic stats, 8 ch/block (round-7 proven; conv1/fallbacks) =====================
template<int IC, int OC>
__global__ void __launch_bounds__(256) conv_stats(const float* __restrict__ in,
                                                  const float* __restrict__ w,
                                                  const float* __restrict__ bias,
                                                  float* __restrict__ outp,
                                                  double* __restrict__ stats) {
  int bz = blockIdx.x;
  int n  = ((bz & 7) << 8) | threadIdx.x;
  int o0 = ((bz >> 3) % (OC / 8)) * 8;
  int b  = bz / (8 * (OC / 8));
  const float* inb = in + b * IC * NPT + n;
  float a[8];
#pragma unroll
  for (int t = 0; t < 8; ++t) a[t] = bias[o0 + t];
  const float* wb = w + o0 * IC;
#pragma unroll 4
  for (int f = 0; f < IC; ++f) {
    float v = inb[f * NPT];
#pragma unroll
    for (int t = 0; t < 8; ++t) a[t] += wb[t * IC + f] * v;
  }
  float* ob = outp + b * OC * NPT + n;
#pragma unroll
  for (int t = 0; t < 8; ++t) ob[(o0 + t) * NPT] = a[t];
  __shared__ double red[4][8][2];
  int lane = threadIdx.x & 63, wid = threadIdx.x >> 6;
#pragma unroll
  for (int j = 0; j < 8; ++j) {
    double s1 = (double)a[j];
    double s2 = (double)a[j] * (double)a[j];
#pragma unroll
    for (int off = 32; off; off >>= 1) { s1 += __shfl_down(s1, off); s2 += __shfl_down(s2, off); }
    if (lane == 0) { red[wid][j][0] = s1; red[wid][j][1] = s2; }
  }
  __syncthreads();
  if (threadIdx.x < 8) {
    int j = threadIdx.x;
    double S1 = red[0][j][0] + red[1][j][0] + red[2][j][0] + red[3][j][0];
    double S2 = red[0][j][1] + red[1][j][1] + red[2][j][1] + red[3][j][1];
    atomicAdd(&stats[o0 + j], S1);
    atomicAdd(&stats[OC + o0 + j], S2);
  }
}

// ===================== conv + atomic stats, 16 ch/block (halves input re-reads; used for mlp3) =====================
template<int IC, int OC>
__global__ void __launch_bounds__(256) conv_stats16(const float* __restrict__ in,
                                                    const float* __restrict__ w,
                                                    const float* __restrict__ bias,
                                                    float* __restrict__ outp,
                                                    double* __restrict__ stats) {
  int bz = blockIdx.x;                           // grid = NB * (OC/16) * 8
  int n  = ((bz & 7) << 8) | threadIdx.x;
  int o0 = ((bz >> 3) % (OC / 16)) * 16;
  int b  = bz / (8 * (OC / 16));
  const float* inb = in + b * IC * NPT + n;
  float a[16];
#pragma unroll
  for (int t = 0; t < 16; ++t) a[t] = bias[o0 + t];
  const float* wb = w + o0 * IC;
#pragma unroll 2
  for (int f = 0; f < IC; ++f) {
    float v = inb[f * NPT];
#pragma unroll
    for (int t = 0; t < 16; ++t) a[t] += wb[t * IC + f] * v;
  }
  float* ob = outp + b * OC * NPT + n;
#pragma unroll
  for (int t = 0; t < 16; ++t) ob[(o0 + t) * NPT] = a[t];
  __shared__ double red[4][16][2];
  int lane = threadIdx.x & 63, wid = threadIdx.x >> 6;
#pragma unroll
  for (int j = 0; j < 16; ++j) {
    double s1 = (double)a[j];
    double s2 = (double)a[j] * (double)a[j];
#pragma unroll
    for (int off = 32; off; off >>= 1) { s1 += __shfl_down(s1, off); s2 += __shfl_down(s2, off); }
    if (lane == 0) { red[wid][j][0] = s1; red[wid][j][1] = s2; }
  }
  __syncthreads();
  if (threadIdx.x < 16) {
    int j = threadIdx.x;
    double S1 = red[0][j][0] + red[1][j][0] + red[2][j][0] + red[3][j][0];
    double S2 = red[0][j][1] + red[1][j][1] + red[2][j][1] + red[3][j][1];
    atomicAdd(&stats[o0 + j], S1);
    atomicAdd(&stats[OC + o0 + j], S2);
  }
}

// ===================== BN finalize + ReLU (+optional residual), float4 (round-7 proven) =====================
template<int C>
__global__ void __launch_bounds__(256) bn_apply(const float* __restrict__ pre,
                                                const float* __restrict__ addsrc,
                                                float* __restrict__ outp,
                                                const double* __restrict__ stats,
                                                const float* __restrict__ gam,
                                                const float* __restrict__ bet,
                                                double inv_cnt) {
  __shared__ float sc[C], sh[C];
  for (int c = threadIdx.x; c < C; c += 256) {
    double mu    = stats[c] * inv_cnt;
    double var   = stats[C + c] * inv_cnt - mu * mu;
    double scale = (double)gam[c] / sqrt(var + EPSI);
    sc[c] = (float)scale;
    sh[c] = (float)((double)bet[c] - mu * scale);
  }
  __syncthreads();
  const float4* pre4 = (const float4*)pre;
  const float4* add4 = (const float4*)addsrc;
  float4* out4 = (float4*)outp;
  int total4 = NB * C * (NPT / 4);
  for (int i = blockIdx.x * 256 + threadIdx.x; i < total4; i += gridDim.x * 256) {
    int c = (i >> 9) & (C - 1);
    float s = sc[c], h = sh[c];
    float4 v = pre4[i];
    v.x = fmaxf(v.x * s + h, 0.f);
    v.y = fmaxf(v.y * s + h, 0.f);
    v.z = fmaxf(v.z * s + h, 0.f);
    v.w = fmaxf(v.w * s + h, 0.f);
    if (addsrc) {
      float4 a = add4[i];
      v.x += a.x; v.y += a.y; v.z += a.z; v.w += a.w;
    }
    out4[i] = v;
  }
}

// ===================== DSgroupMLP (round-7 proven + scalar-load hint): gather + 64x64 FC + max over k =====================
// src[k] is wave-uniform (depends only on wave's point n). readfirstlane makes that
// provable to the compiler -> gather loads become s_load via the scalar cache,
// offloading 2048 VMEM instructions/wave from the vector pipe. Semantically identity.
__global__ void __launch_bounds__(256) dsgroup_kernel(const float* __restrict__ x1,
                                                      const int* __restrict__ idx16,
                                                      const float* __restrict__ wf,
                                                      const float* __restrict__ bfp,
                                                      float* __restrict__ hmax,
                                                      double* __restrict__ stats) {
  __shared__ float wfT[64 * 65];
  __shared__ double dred[4][64][2];
  for (int i = threadIdx.x; i < 64 * 64; i += 256) {
    int o = i >> 6, f = i & 63;
    wfT[f * 65 + o] = wf[i];                     // i = o*64+f
  }
  __syncthreads();
  int lane = threadIdx.x & 63, wid = threadIdx.x >> 6;
  int wave = blockIdx.x * 4 + wid;
  float bo = bfp[lane];
  double s1 = 0.0, s2 = 0.0;
  for (int p = 0; p < 4; ++p) {
    int pt = wave * 4 + p;
    int b = pt >> 11, n = pt & 2047;
    int src[8];
#pragma unroll
    for (int k = 0; k < 8; ++k) {
      int j = k * NPT + n;                       // torch-view scramble: idx[(j>>3), j&7]
      src[k] = __builtin_amdgcn_readfirstlane(idx16[((b * NPT + (j >> 3)) << 4) | (j & 7)]);
    }
    float acc[8];
#pragma unroll
    for (int k = 0; k < 8; ++k) acc[k] = bo;
    const float* x1b = x1 + b * CR * NPT;
    for (int f = 0; f < 64; ++f) {
      float wv = wfT[f * 65 + lane];             // lane = output channel o
      const float* row = x1b + f * NPT;
#pragma unroll
      for (int k = 0; k < 8; ++k) acc[k] += row[src[k]] * wv;
    }
    float hm = acc[0];
#pragma unroll
    for (int k = 0; k < 8; ++k) {
      hm = fmaxf(hm, acc[k]);
      s1 += (double)acc[k];
      s2 += (double)acc[k] * (double)acc[k];
    }
    hmax[(b * CR + lane) * NPT + n] = hm;        // max commutes with BN+ReLU (gamma>0)
  }
  dred[wid][lane][0] = s1; dred[wid][lane][1] = s2;
  __syncthreads();
  if (threadIdx.x < 64) {
    double S1 = dred[0][threadIdx.x][0] + dred[1][threadIdx.x][0] + dred[2][threadIdx.x][0] + dred[3][threadIdx.x][0];
    double S2 = dred[0][threadIdx.x][1] + dred[1][threadIdx.x][1] + dred[2][threadIdx.x][1] + dred[3][threadIdx.x][1];
    atomicAdd(&stats[threadIdx.x], S1);
    atomicAdd(&stats[64 + threadIdx.x], S2);
  }
}

// ===================== lap_fused (round-8/11 VALIDATED): BN_g inline + mean-gather + 64x64 FC =====================
__global__ void __launch_bounds__(256) lap_fused(const float* __restrict__ hpre,
                                                 const int* __restrict__ idx16,
                                                 const float* __restrict__ wl,
                                                 const float* __restrict__ blp,
                                                 float* __restrict__ tpre,
                                                 double* __restrict__ stats,
                                                 const double* __restrict__ stg,
                                                 const float* __restrict__ gg,
                                                 const float* __restrict__ bg) {
  __shared__ float wlT[64 * 65];
  __shared__ double dred[4][64][2];
  __shared__ float vstage[4][64];
  __shared__ float scg[64], shg[64];
  for (int i = threadIdx.x; i < 64 * 64; i += 256) {
    int o = i >> 6, f = i & 63;
    wlT[f * 65 + o] = wl[i];
  }
  if (threadIdx.x < 64) {
    int c = threadIdx.x;
    double mu  = stg[c] / 131072.0;
    double var = stg[64 + c] / 131072.0 - mu * mu;
    double s   = (double)gg[c] / sqrt(var + EPSI);
    scg[c] = (float)s;
    shg[c] = (float)((double)bg[c] - mu * s);
  }
  __syncthreads();
  int lane = threadIdx.x & 63, wid = threadIdx.x >> 6;
  int g = lane >> 4, cc = lane & 15;
  float blv = blp[lane];
  double s1 = 0.0, s2 = 0.0;
  for (int p = 0; p < 4; ++p) {
    int pt = (blockIdx.x * 4 + wid) * 4 + p;
    int b = pt >> 11, n = pt & 2047;
    int ch = n >> 5;                             // gathered CHANNEL is n>>5 (torch-view scramble)
    int r0 = (n & 31) << 6;
    const float* xrow = hpre + (b * CR + ch) * NPT;
    const int* ib = idx16 + ((b * NPT + r0) << 4);
    float sgc = scg[ch], shc = shg[ch];
    float msum = 0.f;
#pragma unroll
    for (int kk = 0; kk < 16; ++kk) {
      int sidx = ib[(((kk << 2) + g) << 4) | cc];
      msum += fmaxf(fmaf(xrow[sidx], sgc, shc), 0.f);    // BN_g inline
    }
    float mval = msum * 0.0625f;
    float xraw = hpre[(b * CR + lane) * NPT + n];
    float xv = fmaxf(fmaf(xraw, scg[lane], shg[lane]), 0.f);
    vstage[wid][lane] = xv - mval;
    float acc = blv;
    for (int f = 0; f < 64; ++f)
      acc += wlT[f * 65 + lane] * vstage[wid][f];
    tpre[(b * CR + lane) * NPT + n] = acc;
    s1 += (double)acc;
    s2 += (double)acc * (double)acc;
  }
  dred[wid][lane][0] = s1; dred[wid][lane][1] = s2;
  __syncthreads();
  if (threadIdx.x < 64) {
    double S1 = dred[0][threadIdx.x][0] + dred[1][threadIdx.x][0] + dred[2][threadIdx.x][0] + dred[3][threadIdx.x][0];
    double S2 = dred[0][threadIdx.x][1] + dred[1][threadIdx.x][1] + dred[2][threadIdx.x][1] + dred[3][threadIdx.x][1];
    atomicAdd(&stats[threadIdx.x], S1);
    atomicAdd(&stats[64 + threadIdx.x], S2);
  }
}

// ===================== conv2_fused (r9, exonerated by r9/r10 identical-absmax analysis): =====================
// x3 = relu(bn_g(h)) + relu(bn_l(t)) computed inline in the load stream; 64->128 conv + stats.
// Bit-identical v to combine_kernel's output (same op sequence).
__global__ void __launch_bounds__(256) conv2_fused(const float* __restrict__ hpre,
                                                   const float* __restrict__ tpre,
                                                   const double* __restrict__ stg,
                                                   const float* __restrict__ gg,
                                                   const float* __restrict__ bg,
                                                   const double* __restrict__ stl,
                                                   const float* __restrict__ gl,
                                                   const float* __restrict__ bel,
                                                   const float* __restrict__ w,
                                                   const float* __restrict__ bias,
                                                   float* __restrict__ outp,
                                                   double* __restrict__ stats) {
  __shared__ float scg[64], shg[64], scl[64], shl[64];
  __shared__ double red[4][8][2];
  if (threadIdx.x < 64) {
    int c = threadIdx.x;
    double mu  = stg[c] / 131072.0;
    double var = stg[64 + c] / 131072.0 - mu * mu;
    double s   = (double)gg[c] / sqrt(var + EPSI);
    scg[c] = (float)s; shg[c] = (float)((double)bg[c] - mu * s);
    double mu2  = stl[c] / 16384.0;
    double var2 = stl[64 + c] / 16384.0 - mu2 * mu2;
    double s2   = (double)gl[c] / sqrt(var2 + EPSI);
    scl[c] = (float)s2; shl[c] = (float)((double)bel[c] - mu2 * s2);
  }
  __syncthreads();
  int bz = blockIdx.x;                           // 1024 blocks
  int n  = ((bz & 7) << 8) | threadIdx.x;
  int o0 = ((bz >> 3) % 16) * 8;
  int b  = bz / 128;
  const float* hb = hpre + b * CR * NPT + n;
  const float* tb = tpre + b * CR * NPT + n;
  float a[8];
#pragma unroll
  for (int t = 0; t < 8; ++t) a[t] = bias[o0 + t];
  const float* wb = w + o0 * CR;
#pragma unroll 4
  for (int f = 0; f < CR; ++f) {
    float hv = hb[f * NPT], tv = tb[f * NPT];
    float v = fmaxf(fmaf(hv, scg[f], shg[f]), 0.f) + fmaxf(fmaf(tv, scl[f], shl[f]), 0.f);
#pragma unroll
    for (int t = 0; t < 8; ++t) a[t] += wb[t * CR + f] * v;
  }
  float* ob = outp + b * NF * NPT + n;
#pragma unroll
  for (int t = 0; t < 8; ++t) ob[(o0 + t) * NPT] = a[t];
  int lane = threadIdx.x & 63, wid = threadIdx.x >> 6;
#pragma unroll
  for (int j = 0; j < 8; ++j) {
    double s1 = (double)a[j];
    double s2 = (double)a[j] * (double)a[j];
#pragma unroll
    for (int off = 32; off; off >>= 1) { s1 += __shfl_down(s1, off); s2 += __shfl_down(s2, off); }
    if (lane == 0) { red[wid][j][0] = s1; red[wid][j][1] = s2; }
  }
  __syncthreads();
  if (threadIdx.x < 8) {
    int j = threadIdx.x;
    double S1 = red[0][j][0] + red[1][j][0] + red[2][j][0] + red[3][j][0];
    double S2 = red[0][j][1] + red[1][j][1] + red[2][j][1] + red[3][j][1];
    atomicAdd(&stats[o0 + j], S1);
    atomicAdd(&stats[NF + o0 + j], S2);
  }
}

// ============================ launch (10 nodes) ============================
extern "C" void kernel_launch(void* const* d_in, const int* in_sizes, int n_in,
                              void* d_out, int out_size, void* d_ws, size_t ws_size,
                              hipStream_t stream) {
  const float* xyz  = (const float*)d_in[0];
  const float* feat = (const float*)d_in[1];
  const float* w1   = (const float*)d_in[2];
  const float* b1   = (const float*)d_in[3];
  const float* g1   = (const float*)d_in[4];
  const float* be1  = (const float*)d_in[5];
  const float* wf   = (const float*)d_in[6];
  const float* bf   = (const float*)d_in[7];
  const float* gg   = (const float*)d_in[8];
  const float* bg   = (const float*)d_in[9];
  const float* wl   = (const float*)d_in[10];
  const float* bl   = (const float*)d_in[11];
  const float* gl   = (const float*)d_in[12];
  const float* bel  = (const float*)d_in[13];
  const float* w2   = (const float*)d_in[14];
  const float* b2   = (const float*)d_in[15];
  const float* g2   = (const float*)d_in[16];
  const float* be2  = (const float*)d_in[17];
  const float* w3   = (const float*)d_in[18];
  const float* b3   = (const float*)d_in[19];
  const float* g3   = (const float*)d_in[20];
  const float* be3  = (const float*)d_in[21];
  float* out = (float*)d_out;

  // d_out scratch (dead before conv3 writes out): x1, tpre, idx16
  float* x1   = out;                       // 4MB
  float* tpre = out + 1048576;             // 4MB
  int*  idx16 = (int*)(out + 2097152);     // 1MB
  // ws: hpre, y2, stats (12MB + 9KB footprint, as all passing rounds)
  float*  hpre  = (float*)d_ws;            // 4MB
  float*  y2    = hpre + 1048576;          // 8MB
  double* stats = (double*)((char*)d_ws + (12u << 20));
  double* st0 = stats;        // 128
  double* stg = stats + 128;  // 128
  double* stl = stats + 256;  // 128
  double* st2 = stats + 384;  // 256
  double* st3 = stats + 640;  // 512

  hipMemsetAsync(stats, 0, 1152 * sizeof(double), stream);

  // 1: kNN
  knn_kernel<<<4096, 256, 0, stream>>>(xyz, idx16);
  // 2: conv1 -> x1 + st0
  conv_stats<128, 64><<<512, 256, 0, stream>>>(feat, w1, b1, x1, st0);
  // 3: bn1 -> x1 in place
  bn_apply<64><<<1024, 256, 0, stream>>>(x1, nullptr, x1, st0, g1, be1, 1.0 / 16384.0);
  // 4: dsgroup -> hpre (pre-BN max) + stg
  dsgroup_kernel<<<1024, 256, 0, stream>>>(x1, idx16, wf, bf, hpre, stg);
  // 5: lap (BN_g inline) -> tpre + stl
  lap_fused<<<1024, 256, 0, stream>>>(hpre, idx16, wl, bl, tpre, stl, stg, gg, bg);
  // 6: conv2 (x3 inline from hpre,tpre) -> y2 + st2
  conv2_fused<<<1024, 256, 0, stream>>>(hpre, tpre, stg, gg, bg, stl, gl, bel, w2, b2, y2, st2);
  // 7: bn2 + feat residual -> y2 in place
  bn_apply<128><<<1024, 256, 0, stream>>>(y2, feat, y2, st2, g2, be2, 1.0 / 16384.0);
  // 8: conv3 (16 ch/block) -> out + st3
  conv_stats16<128, 256><<<1024, 256, 0, stream>>>(y2, w3, b3, out, st3);
  // 9: bn3 -> out in place
  bn_apply<256><<<1024, 256, 0, stream>>>(out, nullptr, out, st3, g3, be3, 1.0 / 16384.0);
}

// Round 13
// 256.989 us; speedup vs baseline: 1.1913x; 1.1913x over previous
//
#include <hip/hip_runtime.h>

#define NB   8
#define NPT  2048
#define NF   128
#define CR   64
#define EPSI 1e-5

// ============================ kNN (top-16, 2-D, exact f32+FMA emulation of np/jax) ============================
// PROVEN (rounds 6/7/11/12): passes, ~105 us, VALU-issue-bound. FROZEN.
__global__ void __launch_bounds__(256) knn_kernel(const float* __restrict__ xyz,
                                                  int* __restrict__ idx16) {
  __shared__ float px[NPT], py[NPT], sxx[NPT];
  int b = blockIdx.x >> 9;
  const float* xb = xyz + b * 3 * NPT;
  for (int i = threadIdx.x; i < NPT; i += 256) {
    float x = xb[i], y = xb[NPT + i];
    px[i] = x; py[i] = y;
    sxx[i] = __fadd_rn(__fmul_rn(x, x), __fmul_rn(y, y));
  }
  __syncthreads();
  int lane = threadIdx.x & 63, wid = threadIdx.x >> 6;
  int q = ((blockIdx.x & 511) << 2) | wid;
  float qx = px[q], qy = py[q], qxx = sxx[q];
  float dc[32];
#pragma unroll 4
  for (int j = 0; j < 32; ++j) {
    int m = lane + (j << 6);
    float inner_s = __fmaf_rn(qy, py[m], __fmul_rn(qx, px[m]));
    dc[j] = __fadd_rn(__fsub_rn(qxx, __fmul_rn(2.0f, inner_s)), sxx[m]);
  }
  int keep = 0;
  for (int r = 0; r < 16; ++r) {
    float dmin = dc[0]; int jmin = 0;
#pragma unroll
    for (int j = 1; j < 32; ++j) {
      bool better = dc[j] < dmin;
      dmin = better ? dc[j] : dmin;
      jmin = better ? j : jmin;
    }
    float hd = dmin;
    int   hm = lane + (jmin << 6);
#pragma unroll
    for (int off = 1; off < 64; off <<= 1) {
      float od = __shfl_xor(hd, off);
      int   om = __shfl_xor(hm, off);
      bool take = (od < hd) || (od == hd && om < hm);
      hd = take ? od : hd;
      hm = take ? om : hm;
    }
    if (lane == r) keep = hm;
    bool own = (hm & 63) == lane;
    int jw = hm >> 6;
#pragma unroll
    for (int j = 0; j < 32; ++j)
      dc[j] = (own && j == jw) ? 1e38f : dc[j];
  }
  if (lane < 16) idx16[((b * NPT + q) << 4) + lane] = keep;
}

// ===================== generic conv + atomic stats, 8 ch/block (round-7/11 proven) =====================
template<int IC, int OC>
__global__ void __launch_bounds__(256) conv_stats(const float* __restrict__ in,
                                                  const float* __restrict__ w,
                                                  const float* __restrict__ bias,
                                                  float* __restrict__ outp,
                                                  double* __restrict__ stats) {
  int bz = blockIdx.x;
  int n  = ((bz & 7) << 8) | threadIdx.x;
  int o0 = ((bz >> 3) % (OC / 8)) * 8;
  int b  = bz / (8 * (OC / 8));
  const float* inb = in + b * IC * NPT + n;
  float a[8];
#pragma unroll
  for (int t = 0; t < 8; ++t) a[t] = bias[o0 + t];
  const float* wb = w + o0 * IC;
#pragma unroll 4
  for (int f = 0; f < IC; ++f) {
    float v = inb[f * NPT];
#pragma unroll
    for (int t = 0; t < 8; ++t) a[t] += wb[t * IC + f] * v;
  }
  float* ob = outp + b * OC * NPT + n;
#pragma unroll
  for (int t = 0; t < 8; ++t) ob[(o0 + t) * NPT] = a[t];
  __shared__ double red[4][8][2];
  int lane = threadIdx.x & 63, wid = threadIdx.x >> 6;
#pragma unroll
  for (int j = 0; j < 8; ++j) {
    double s1 = (double)a[j];
    double s2 = (double)a[j] * (double)a[j];
#pragma unroll
    for (int off = 32; off; off >>= 1) { s1 += __shfl_down(s1, off); s2 += __shfl_down(s2, off); }
    if (lane == 0) { red[wid][j][0] = s1; red[wid][j][1] = s2; }
  }
  __syncthreads();
  if (threadIdx.x < 8) {
    int j = threadIdx.x;
    double S1 = red[0][j][0] + red[1][j][0] + red[2][j][0] + red[3][j][0];
    double S2 = red[0][j][1] + red[1][j][1] + red[2][j][1] + red[3][j][1];
    atomicAdd(&stats[o0 + j], S1);
    atomicAdd(&stats[OC + o0 + j], S2);
  }
}

// ===================== BN finalize + ReLU (+optional residual), float4 (round-7 proven) =====================
template<int C>
__global__ void __launch_bounds__(256) bn_apply(const float* __restrict__ pre,
                                                const float* __restrict__ addsrc,
                                                float* __restrict__ outp,
                                                const double* __restrict__ stats,
                                                const float* __restrict__ gam,
                                                const float* __restrict__ bet,
                                                double inv_cnt) {
  __shared__ float sc[C], sh[C];
  for (int c = threadIdx.x; c < C; c += 256) {
    double mu    = stats[c] * inv_cnt;
    double var   = stats[C + c] * inv_cnt - mu * mu;
    double scale = (double)gam[c] / sqrt(var + EPSI);
    sc[c] = (float)scale;
    sh[c] = (float)((double)bet[c] - mu * scale);
  }
  __syncthreads();
  const float4* pre4 = (const float4*)pre;
  const float4* add4 = (const float4*)addsrc;
  float4* out4 = (float4*)outp;
  int total4 = NB * C * (NPT / 4);
  for (int i = blockIdx.x * 256 + threadIdx.x; i < total4; i += gridDim.x * 256) {
    int c = (i >> 9) & (C - 1);
    float s = sc[c], h = sh[c];
    float4 v = pre4[i];
    v.x = fmaxf(v.x * s + h, 0.f);
    v.y = fmaxf(v.y * s + h, 0.f);
    v.z = fmaxf(v.z * s + h, 0.f);
    v.w = fmaxf(v.w * s + h, 0.f);
    if (addsrc) {
      float4 a = add4[i];
      v.x += a.x; v.y += a.y; v.z += a.z; v.w += a.w;
    }
    out4[i] = v;
  }
}

// ===================== zconv: z = Wf·relu(bn1(x1pre)) + bf, stored TRANSPOSED zT[n][o] =====================
// The DSgroup FC commutes with the gather (it acts on channels, the gather permutes points):
// h[o,n,k] = z[o, src(n,k)]. Same bias-first, f-ascending FMA chain as dsgroup -> bit-identical h.
// bn1 folded into the load (saves the bn1 pass; x1pre consumed only here).
__global__ void __launch_bounds__(256) zconv_kernel(const float* __restrict__ x1pre,
                                                    const double* __restrict__ st0,
                                                    const float* __restrict__ g1,
                                                    const float* __restrict__ be1,
                                                    const float* __restrict__ wf,
                                                    const float* __restrict__ bfp,
                                                    float* __restrict__ zT) {
  __shared__ float sc[64], sh[64];
  if (threadIdx.x < 64) {
    int c = threadIdx.x;
    double mu  = st0[c] / 16384.0;
    double var = st0[64 + c] / 16384.0 - mu * mu;
    double s   = (double)g1[c] / sqrt(var + EPSI);
    sc[c] = (float)s;
    sh[c] = (float)((double)be1[c] - mu * s);
  }
  __syncthreads();
  int bz = blockIdx.x;                           // 512 blocks: [b(8)][og(8)][ng(8)]
  int n  = ((bz & 7) << 8) | threadIdx.x;
  int o0 = ((bz >> 3) % 8) * 8;
  int b  = bz / 64;
  const float* inb = x1pre + b * CR * NPT + n;
  float a[8];
#pragma unroll
  for (int t = 0; t < 8; ++t) a[t] = bfp[o0 + t];
  const float* wb = wf + o0 * CR;
#pragma unroll 4
  for (int f = 0; f < CR; ++f) {
    float v = fmaxf(fmaf(inb[f * NPT], sc[f], sh[f]), 0.f);   // bn1 + relu inline
#pragma unroll
    for (int t = 0; t < 8; ++t) a[t] += wb[t * CR + f] * v;
  }
  float* zp = zT + ((b * NPT + n) << 6) + o0;    // zT[b][n][o]
  *(float4*)(zp)     = make_float4(a[0], a[1], a[2], a[3]);
  *(float4*)(zp + 4) = make_float4(a[4], a[5], a[6], a[7]);
}

// ===================== gathermax: h[o,n,k] = zT[src(n,k)][o]; max over k + f64 stats =====================
// 8 coalesced 256B wave-loads per point (vs 512 broadcast loads in the old dsgroup).
// Scramble decode verbatim from the proven dsgroup. Max/stat order identical.
__global__ void __launch_bounds__(256) gathermax_kernel(const float* __restrict__ zT,
                                                        const int* __restrict__ idx16,
                                                        float* __restrict__ hmax,
                                                        double* __restrict__ stats) {
  __shared__ double dred[4][64][2];
  int lane = threadIdx.x & 63, wid = threadIdx.x >> 6;
  int wave = blockIdx.x * 4 + wid;               // 1024 blocks, 4 pts/wave
  double s1 = 0.0, s2 = 0.0;
  for (int p = 0; p < 4; ++p) {
    int pt = wave * 4 + p;
    int b = pt >> 11, n = pt & 2047;
    const float* zb = zT + ((b * NPT) << 6);
    float vals[8];
#pragma unroll
    for (int k = 0; k < 8; ++k) {
      int j = k * NPT + n;                       // torch-view scramble: idx[(j>>3), j&7]
      int src = idx16[((b * NPT + (j >> 3)) << 4) | (j & 7)];
      vals[k] = zb[(src << 6) + lane];           // coalesced: 64 lanes read 256B
    }
    float hm = vals[0];
#pragma unroll
    for (int k = 0; k < 8; ++k) {
      hm = fmaxf(hm, vals[k]);
      s1 += (double)vals[k];
      s2 += (double)vals[k] * (double)vals[k];
    }
    hmax[(b * CR + lane) * NPT + n] = hm;        // max commutes with BN+ReLU (gamma>0)
  }
  dred[wid][lane][0] = s1; dred[wid][lane][1] = s2;
  __syncthreads();
  if (threadIdx.x < 64) {
    double S1 = dred[0][threadIdx.x][0] + dred[1][threadIdx.x][0] + dred[2][threadIdx.x][0] + dred[3][threadIdx.x][0];
    double S2 = dred[0][threadIdx.x][1] + dred[1][threadIdx.x][1] + dred[2][threadIdx.x][1] + dred[3][threadIdx.x][1];
    atomicAdd(&stats[threadIdx.x], S1);
    atomicAdd(&stats[64 + threadIdx.x], S2);
  }
}

// ===================== lap_fused (round-8/11/12 VALIDATED): BN_g inline + mean-gather + 64x64 FC =====================
__global__ void __launch_bounds__(256) lap_fused(const float* __restrict__ hpre,
                                                 const int* __restrict__ idx16,
                                                 const float* __restrict__ wl,
                                                 const float* __restrict__ blp,
                                                 float* __restrict__ tpre,
                                                 double* __restrict__ stats,
                                                 const double* __restrict__ stg,
                                                 const float* __restrict__ gg,
                                                 const float* __restrict__ bg) {
  __shared__ float wlT[64 * 65];
  __shared__ double dred[4][64][2];
  __shared__ float vstage[4][64];
  __shared__ float scg[64], shg[64];
  for (int i = threadIdx.x; i < 64 * 64; i += 256) {
    int o = i >> 6, f = i & 63;
    wlT[f * 65 + o] = wl[i];
  }
  if (threadIdx.x < 64) {
    int c = threadIdx.x;
    double mu  = stg[c] / 131072.0;
    double var = stg[64 + c] / 131072.0 - mu * mu;
    double s   = (double)gg[c] / sqrt(var + EPSI);
    scg[c] = (float)s;
    shg[c] = (float)((double)bg[c] - mu * s);
  }
  __syncthreads();
  int lane = threadIdx.x & 63, wid = threadIdx.x >> 6;
  int g = lane >> 4, cc = lane & 15;
  float blv = blp[lane];
  double s1 = 0.0, s2 = 0.0;
  for (int p = 0; p < 4; ++p) {
    int pt = (blockIdx.x * 4 + wid) * 4 + p;
    int b = pt >> 11, n = pt & 2047;
    int ch = n >> 5;                             // gathered CHANNEL is n>>5 (torch-view scramble)
    int r0 = (n & 31) << 6;
    const float* xrow = hpre + (b * CR + ch) * NPT;
    const int* ib = idx16 + ((b * NPT + r0) << 4);
    float sgc = scg[ch], shc = shg[ch];
    float msum = 0.f;
#pragma unroll
    for (int kk = 0; kk < 16; ++kk) {
      int sidx = ib[(((kk << 2) + g) << 4) | cc];
      msum += fmaxf(fmaf(xrow[sidx], sgc, shc), 0.f);    // BN_g inline
    }
    float mval = msum * 0.0625f;
    float xraw = hpre[(b * CR + lane) * NPT + n];
    float xv = fmaxf(fmaf(xraw, scg[lane], shg[lane]), 0.f);
    vstage[wid][lane] = xv - mval;
    float acc = blv;
    for (int f = 0; f < 64; ++f)
      acc += wlT[f * 65 + lane] * vstage[wid][f];
    tpre[(b * CR + lane) * NPT + n] = acc;
    s1 += (double)acc;
    s2 += (double)acc * (double)acc;
  }
  dred[wid][lane][0] = s1; dred[wid][lane][1] = s2;
  __syncthreads();
  if (threadIdx.x < 64) {
    double S1 = dred[0][threadIdx.x][0] + dred[1][threadIdx.x][0] + dred[2][threadIdx.x][0] + dred[3][threadIdx.x][0];
    double S2 = dred[0][threadIdx.x][1] + dred[1][threadIdx.x][1] + dred[2][threadIdx.x][1] + dred[3][threadIdx.x][1];
    atomicAdd(&stats[threadIdx.x], S1);
    atomicAdd(&stats[64 + threadIdx.x], S2);
  }
}

// ===================== conv2_fused (r12-proven): x3 = relu(bn_g(h)) + relu(bn_l(t)) inline; 64->128 conv =====================
__global__ void __launch_bounds__(256) conv2_fused(const float* __restrict__ hpre,
                                                   const float* __restrict__ tpre,
                                                   const double* __restrict__ stg,
                                                   const float* __restrict__ gg,
                                                   const float* __restrict__ bg,
                                                   const double* __restrict__ stl,
                                                   const float* __restrict__ gl,
                                                   const float* __restrict__ bel,
                                                   const float* __restrict__ w,
                                                   const float* __restrict__ bias,
                                                   float* __restrict__ outp,
                                                   double* __restrict__ stats) {
  __shared__ float scg[64], shg[64], scl[64], shl[64];
  __shared__ double red[4][8][2];
  if (threadIdx.x < 64) {
    int c = threadIdx.x;
    double mu  = stg[c] / 131072.0;
    double var = stg[64 + c] / 131072.0 - mu * mu;
    double s   = (double)gg[c] / sqrt(var + EPSI);
    scg[c] = (float)s; shg[c] = (float)((double)bg[c] - mu * s);
    double mu2  = stl[c] / 16384.0;
    double var2 = stl[64 + c] / 16384.0 - mu2 * mu2;
    double s2   = (double)gl[c] / sqrt(var2 + EPSI);
    scl[c] = (float)s2; shl[c] = (float)((double)bel[c] - mu2 * s2);
  }
  __syncthreads();
  int bz = blockIdx.x;                           // 1024 blocks
  int n  = ((bz & 7) << 8) | threadIdx.x;
  int o0 = ((bz >> 3) % 16) * 8;
  int b  = bz / 128;
  const float* hb = hpre + b * CR * NPT + n;
  const float* tb = tpre + b * CR * NPT + n;
  float a[8];
#pragma unroll
  for (int t = 0; t < 8; ++t) a[t] = bias[o0 + t];
  const float* wb = w + o0 * CR;
#pragma unroll 4
  for (int f = 0; f < CR; ++f) {
    float hv = hb[f * NPT], tv = tb[f * NPT];
    float v = fmaxf(fmaf(hv, scg[f], shg[f]), 0.f) + fmaxf(fmaf(tv, scl[f], shl[f]), 0.f);
#pragma unroll
    for (int t = 0; t < 8; ++t) a[t] += wb[t * CR + f] * v;
  }
  float* ob = outp + b * NF * NPT + n;
#pragma unroll
  for (int t = 0; t < 8; ++t) ob[(o0 + t) * NPT] = a[t];
  int lane = threadIdx.x & 63, wid = threadIdx.x >> 6;
#pragma unroll
  for (int j = 0; j < 8; ++j) {
    double s1 = (double)a[j];
    double s2 = (double)a[j] * (double)a[j];
#pragma unroll
    for (int off = 32; off; off >>= 1) { s1 += __shfl_down(s1, off); s2 += __shfl_down(s2, off); }
    if (lane == 0) { red[wid][j][0] = s1; red[wid][j][1] = s2; }
  }
  __syncthreads();
  if (threadIdx.x < 8) {
    int j = threadIdx.x;
    double S1 = red[0][j][0] + red[1][j][0] + red[2][j][0] + red[3][j][0];
    double S2 = red[0][j][1] + red[1][j][1] + red[2][j][1] + red[3][j][1];
    atomicAdd(&stats[o0 + j], S1);
    atomicAdd(&stats[NF + o0 + j], S2);
  }
}

// ============================ launch (10 nodes) ============================
extern "C" void kernel_launch(void* const* d_in, const int* in_sizes, int n_in,
                              void* d_out, int out_size, void* d_ws, size_t ws_size,
                              hipStream_t stream) {
  const float* xyz  = (const float*)d_in[0];
  const float* feat = (const float*)d_in[1];
  const float* w1   = (const float*)d_in[2];
  const float* b1   = (const float*)d_in[3];
  const float* g1   = (const float*)d_in[4];
  const float* be1  = (const float*)d_in[5];
  const float* wf   = (const float*)d_in[6];
  const float* bf   = (const float*)d_in[7];
  const float* gg   = (const float*)d_in[8];
  const float* bg   = (const float*)d_in[9];
  const float* wl   = (const float*)d_in[10];
  const float* bl   = (const float*)d_in[11];
  const float* gl   = (const float*)d_in[12];
  const float* bel  = (const float*)d_in[13];
  const float* w2   = (const float*)d_in[14];
  const float* b2   = (const float*)d_in[15];
  const float* g2   = (const float*)d_in[16];
  const float* be2  = (const float*)d_in[17];
  const float* w3   = (const float*)d_in[18];
  const float* b3   = (const float*)d_in[19];
  const float* g3   = (const float*)d_in[20];
  const float* be3  = (const float*)d_in[21];
  float* out = (float*)d_out;

  // d_out scratch (all dead before conv3 writes out):
  float* x1pre = out;                      // 4MB  (pre-BN conv1 out; consumed by zconv)
  float* tpre  = out + 1048576;            // 4MB
  int*  idx16  = (int*)(out + 2097152);    // 1MB
  float* zT    = out + 2359296;            // 4MB  zT[b][n][64] (out offset 9MB..13MB)
  // ws: hpre, y2, stats (12MB + 9KB footprint, as all passing rounds)
  float*  hpre  = (float*)d_ws;            // 4MB
  float*  y2    = hpre + 1048576;          // 8MB
  double* stats = (double*)((char*)d_ws + (12u << 20));
  double* st0 = stats;        // 128
  double* stg = stats + 128;  // 128
  double* stl = stats + 256;  // 128
  double* st2 = stats + 384;  // 256
  double* st3 = stats + 640;  // 512

  hipMemsetAsync(stats, 0, 1152 * sizeof(double), stream);

  // 1: kNN
  knn_kernel<<<4096, 256, 0, stream>>>(xyz, idx16);
  // 2: conv1 -> x1pre + st0
  conv_stats<128, 64><<<512, 256, 0, stream>>>(feat, w1, b1, x1pre, st0);
  // 3: zconv (bn1 inline) -> zT
  zconv_kernel<<<512, 256, 0, stream>>>(x1pre, st0, g1, be1, wf, bf, zT);
  // 4: gathermax -> hpre (pre-BN max) + stg
  gathermax_kernel<<<1024, 256, 0, stream>>>(zT, idx16, hpre, stg);
  // 5: lap (BN_g inline) -> tpre + stl
  lap_fused<<<1024, 256, 0, stream>>>(hpre, idx16, wl, bl, tpre, stl, stg, gg, bg);
  // 6: conv2 (x3 inline from hpre,tpre) -> y2 + st2
  conv2_fused<<<1024, 256, 0, stream>>>(hpre, tpre, stg, gg, bg, stl, gl, bel, w2, b2, y2, st2);
  // 7: bn2 + feat residual -> y2 in place
  bn_apply<128><<<1024, 256, 0, stream>>>(y2, feat, y2, st2, g2, be2, 1.0 / 16384.0);
  // 8: conv3 -> out + st3
  conv_stats<128, 256><<<2048, 256, 0, stream>>>(y2, w3, b3, out, st3);
  // 9: bn3 -> out in place
  bn_apply<256><<<1024, 256, 0, stream>>>(out, nullptr, out, st3, g3, be3, 1.0 / 16384.0);
}

// Round 14
// 253.774 us; speedup vs baseline: 1.2064x; 1.0127x over previous
//
#include <hip/hip_runtime.h>

#define NB   8
#define NPT  2048
#define NF   128
#define CR   64
#define EPSI 1e-5

// ============================ kNN (top-16, 2-D, exact f32+FMA emulation of np/jax) ============================
// PROVEN selection algebra (rounds 6..13). This round: mask pass scalarized —
// hm is wave-uniform after the butterfly, so readfirstlane (identity) moves the
// slot compare to the scalar pipe; winner masking costs ~2 VALU/round instead of ~90.
__global__ void __launch_bounds__(256) knn_kernel(const float* __restrict__ xyz,
                                                  int* __restrict__ idx16) {
  __shared__ float px[NPT], py[NPT], sxx[NPT];
  int b = blockIdx.x >> 9;
  const float* xb = xyz + b * 3 * NPT;
  for (int i = threadIdx.x; i < NPT; i += 256) {
    float x = xb[i], y = xb[NPT + i];
    px[i] = x; py[i] = y;
    sxx[i] = __fadd_rn(__fmul_rn(x, x), __fmul_rn(y, y));
  }
  __syncthreads();
  int lane = threadIdx.x & 63, wid = threadIdx.x >> 6;
  int q = ((blockIdx.x & 511) << 2) | wid;
  float qx = px[q], qy = py[q], qxx = sxx[q];
  float dc[32];
#pragma unroll 4
  for (int j = 0; j < 32; ++j) {
    int m = lane + (j << 6);
    float inner_s = __fmaf_rn(qy, py[m], __fmul_rn(qx, px[m]));
    dc[j] = __fadd_rn(__fsub_rn(qxx, __fmul_rn(2.0f, inner_s)), sxx[m]);
  }
  int keep = 0;
  for (int r = 0; r < 16; ++r) {
    float dmin = dc[0]; int jmin = 0;
#pragma unroll
    for (int j = 1; j < 32; ++j) {
      bool better = dc[j] < dmin;
      dmin = better ? dc[j] : dmin;
      jmin = better ? j : jmin;
    }
    float hd = dmin;
    int   hm = lane + (jmin << 6);
#pragma unroll
    for (int off = 1; off < 64; off <<= 1) {
      float od = __shfl_xor(hd, off);
      int   om = __shfl_xor(hm, off);
      bool take = (od < hd) || (od == hd && om < hm);
      hd = take ? od : hd;
      hm = take ? om : hm;
    }
    if (lane == r) keep = hm;
    // hm is wave-uniform here; readfirstlane is an identity that pins it to SGPR
    unsigned rf = (unsigned)__builtin_amdgcn_readfirstlane(hm);
    bool own = (rf & 63u) == (unsigned)lane;
    int jw = (int)(rf >> 6);
#pragma unroll
    for (int j = 0; j < 32; ++j)
      if (j == jw)                               // scalar cmp + branch (jw uniform)
        dc[j] = own ? 1e38f : dc[j];
  }
  if (lane < 16) idx16[((b * NPT + q) << 4) + lane] = keep;
}

// ===================== generic conv + atomic stats, 8 ch/block (round-7/11 proven; conv1) =====================
template<int IC, int OC>
__global__ void __launch_bounds__(256) conv_stats(const float* __restrict__ in,
                                                  const float* __restrict__ w,
                                                  const float* __restrict__ bias,
                                                  float* __restrict__ outp,
                                                  double* __restrict__ stats) {
  int bz = blockIdx.x;
  int n  = ((bz & 7) << 8) | threadIdx.x;
  int o0 = ((bz >> 3) % (OC / 8)) * 8;
  int b  = bz / (8 * (OC / 8));
  const float* inb = in + b * IC * NPT + n;
  float a[8];
#pragma unroll
  for (int t = 0; t < 8; ++t) a[t] = bias[o0 + t];
  const float* wb = w + o0 * IC;
#pragma unroll 4
  for (int f = 0; f < IC; ++f) {
    float v = inb[f * NPT];
#pragma unroll
    for (int t = 0; t < 8; ++t) a[t] += wb[t * IC + f] * v;
  }
  float* ob = outp + b * OC * NPT + n;
#pragma unroll
  for (int t = 0; t < 8; ++t) ob[(o0 + t) * NPT] = a[t];
  __shared__ double red[4][8][2];
  int lane = threadIdx.x & 63, wid = threadIdx.x >> 6;
#pragma unroll
  for (int j = 0; j < 8; ++j) {
    double s1 = (double)a[j];
    double s2 = (double)a[j] * (double)a[j];
#pragma unroll
    for (int off = 32; off; off >>= 1) { s1 += __shfl_down(s1, off); s2 += __shfl_down(s2, off); }
    if (lane == 0) { red[wid][j][0] = s1; red[wid][j][1] = s2; }
  }
  __syncthreads();
  if (threadIdx.x < 8) {
    int j = threadIdx.x;
    double S1 = red[0][j][0] + red[1][j][0] + red[2][j][0] + red[3][j][0];
    double S2 = red[0][j][1] + red[1][j][1] + red[2][j][1] + red[3][j][1];
    atomicAdd(&stats[o0 + j], S1);
    atomicAdd(&stats[OC + o0 + j], S2);
  }
}

// ===================== BN finalize + ReLU, float4 (round-7 proven; used for bn3) =====================
template<int C>
__global__ void __launch_bounds__(256) bn_apply(const float* __restrict__ pre,
                                                const float* __restrict__ addsrc,
                                                float* __restrict__ outp,
                                                const double* __restrict__ stats,
                                                const float* __restrict__ gam,
                                                const float* __restrict__ bet,
                                                double inv_cnt) {
  __shared__ float sc[C], sh[C];
  for (int c = threadIdx.x; c < C; c += 256) {
    double mu    = stats[c] * inv_cnt;
    double var   = stats[C + c] * inv_cnt - mu * mu;
    double scale = (double)gam[c] / sqrt(var + EPSI);
    sc[c] = (float)scale;
    sh[c] = (float)((double)bet[c] - mu * scale);
  }
  __syncthreads();
  const float4* pre4 = (const float4*)pre;
  const float4* add4 = (const float4*)addsrc;
  float4* out4 = (float4*)outp;
  int total4 = NB * C * (NPT / 4);
  for (int i = blockIdx.x * 256 + threadIdx.x; i < total4; i += gridDim.x * 256) {
    int c = (i >> 9) & (C - 1);
    float s = sc[c], h = sh[c];
    float4 v = pre4[i];
    v.x = fmaxf(v.x * s + h, 0.f);
    v.y = fmaxf(v.y * s + h, 0.f);
    v.z = fmaxf(v.z * s + h, 0.f);
    v.w = fmaxf(v.w * s + h, 0.f);
    if (addsrc) {
      float4 a = add4[i];
      v.x += a.x; v.y += a.y; v.z += a.z; v.w += a.w;
    }
    out4[i] = v;
  }
}

// ===================== zconv (r13-proven): z = Wf·relu(bn1(x1pre)) + bf, stored zT[n][o] =====================
__global__ void __launch_bounds__(256) zconv_kernel(const float* __restrict__ x1pre,
                                                    const double* __restrict__ st0,
                                                    const float* __restrict__ g1,
                                                    const float* __restrict__ be1,
                                                    const float* __restrict__ wf,
                                                    const float* __restrict__ bfp,
                                                    float* __restrict__ zT) {
  __shared__ float sc[64], sh[64];
  if (threadIdx.x < 64) {
    int c = threadIdx.x;
    double mu  = st0[c] / 16384.0;
    double var = st0[64 + c] / 16384.0 - mu * mu;
    double s   = (double)g1[c] / sqrt(var + EPSI);
    sc[c] = (float)s;
    sh[c] = (float)((double)be1[c] - mu * s);
  }
  __syncthreads();
  int bz = blockIdx.x;                           // 512 blocks: [b(8)][og(8)][ng(8)]
  int n  = ((bz & 7) << 8) | threadIdx.x;
  int o0 = ((bz >> 3) % 8) * 8;
  int b  = bz / 64;
  const float* inb = x1pre + b * CR * NPT + n;
  float a[8];
#pragma unroll
  for (int t = 0; t < 8; ++t) a[t] = bfp[o0 + t];
  const float* wb = wf + o0 * CR;
#pragma unroll 4
  for (int f = 0; f < CR; ++f) {
    float v = fmaxf(fmaf(inb[f * NPT], sc[f], sh[f]), 0.f);   // bn1 + relu inline
#pragma unroll
    for (int t = 0; t < 8; ++t) a[t] += wb[t * CR + f] * v;
  }
  float* zp = zT + ((b * NPT + n) << 6) + o0;    // zT[b][n][o]
  *(float4*)(zp)     = make_float4(a[0], a[1], a[2], a[3]);
  *(float4*)(zp + 4) = make_float4(a[4], a[5], a[6], a[7]);
}

// ===================== gathermax (r13-proven): h[o,n,k] = zT[src(n,k)][o]; max over k + f64 stats =====================
__global__ void __launch_bounds__(256) gathermax_kernel(const float* __restrict__ zT,
                                                        const int* __restrict__ idx16,
                                                        float* __restrict__ hmax,
                                                        double* __restrict__ stats) {
  __shared__ double dred[4][64][2];
  int lane = threadIdx.x & 63, wid = threadIdx.x >> 6;
  int wave = blockIdx.x * 4 + wid;               // 1024 blocks, 4 pts/wave
  double s1 = 0.0, s2 = 0.0;
  for (int p = 0; p < 4; ++p) {
    int pt = wave * 4 + p;
    int b = pt >> 11, n = pt & 2047;
    const float* zb = zT + ((b * NPT) << 6);
    float vals[8];
#pragma unroll
    for (int k = 0; k < 8; ++k) {
      int j = k * NPT + n;                       // torch-view scramble: idx[(j>>3), j&7]
      int src = idx16[((b * NPT + (j >> 3)) << 4) | (j & 7)];
      vals[k] = zb[(src << 6) + lane];           // coalesced: 64 lanes read 256B
    }
    float hm = vals[0];
#pragma unroll
    for (int k = 0; k < 8; ++k) {
      hm = fmaxf(hm, vals[k]);
      s1 += (double)vals[k];
      s2 += (double)vals[k] * (double)vals[k];
    }
    hmax[(b * CR + lane) * NPT + n] = hm;        // max commutes with BN+ReLU (gamma>0)
  }
  dred[wid][lane][0] = s1; dred[wid][lane][1] = s2;
  __syncthreads();
  if (threadIdx.x < 64) {
    double S1 = dred[0][threadIdx.x][0] + dred[1][threadIdx.x][0] + dred[2][threadIdx.x][0] + dred[3][threadIdx.x][0];
    double S2 = dred[0][threadIdx.x][1] + dred[1][threadIdx.x][1] + dred[2][threadIdx.x][1] + dred[3][threadIdx.x][1];
    atomicAdd(&stats[threadIdx.x], S1);
    atomicAdd(&stats[64 + threadIdx.x], S2);
  }
}

// ===================== lap_fused (rounds 8/11/12/13 VALIDATED): BN_g inline + mean-gather + 64x64 FC =====================
__global__ void __launch_bounds__(256) lap_fused(const float* __restrict__ hpre,
                                                 const int* __restrict__ idx16,
                                                 const float* __restrict__ wl,
                                                 const float* __restrict__ blp,
                                                 float* __restrict__ tpre,
                                                 double* __restrict__ stats,
                                                 const double* __restrict__ stg,
                                                 const float* __restrict__ gg,
                                                 const float* __restrict__ bg) {
  __shared__ float wlT[64 * 65];
  __shared__ double dred[4][64][2];
  __shared__ float vstage[4][64];
  __shared__ float scg[64], shg[64];
  for (int i = threadIdx.x; i < 64 * 64; i += 256) {
    int o = i >> 6, f = i & 63;
    wlT[f * 65 + o] = wl[i];
  }
  if (threadIdx.x < 64) {
    int c = threadIdx.x;
    double mu  = stg[c] / 131072.0;
    double var = stg[64 + c] / 131072.0 - mu * mu;
    double s   = (double)gg[c] / sqrt(var + EPSI);
    scg[c] = (float)s;
    shg[c] = (float)((double)bg[c] - mu * s);
  }
  __syncthreads();
  int lane = threadIdx.x & 63, wid = threadIdx.x >> 6;
  int g = lane >> 4, cc = lane & 15;
  float blv = blp[lane];
  double s1 = 0.0, s2 = 0.0;
  for (int p = 0; p < 4; ++p) {
    int pt = (blockIdx.x * 4 + wid) * 4 + p;
    int b = pt >> 11, n = pt & 2047;
    int ch = n >> 5;                             // gathered CHANNEL is n>>5 (torch-view scramble)
    int r0 = (n & 31) << 6;
    const float* xrow = hpre + (b * CR + ch) * NPT;
    const int* ib = idx16 + ((b * NPT + r0) << 4);
    float sgc = scg[ch], shc = shg[ch];
    float msum = 0.f;
#pragma unroll
    for (int kk = 0; kk < 16; ++kk) {
      int sidx = ib[(((kk << 2) + g) << 4) | cc];
      msum += fmaxf(fmaf(xrow[sidx], sgc, shc), 0.f);    // BN_g inline
    }
    float mval = msum * 0.0625f;
    float xraw = hpre[(b * CR + lane) * NPT + n];
    float xv = fmaxf(fmaf(xraw, scg[lane], shg[lane]), 0.f);
    vstage[wid][lane] = xv - mval;
    float acc = blv;
    for (int f = 0; f < 64; ++f)
      acc += wlT[f * 65 + lane] * vstage[wid][f];
    tpre[(b * CR + lane) * NPT + n] = acc;
    s1 += (double)acc;
    s2 += (double)acc * (double)acc;
  }
  dred[wid][lane][0] = s1; dred[wid][lane][1] = s2;
  __syncthreads();
  if (threadIdx.x < 64) {
    double S1 = dred[0][threadIdx.x][0] + dred[1][threadIdx.x][0] + dred[2][threadIdx.x][0] + dred[3][threadIdx.x][0];
    double S2 = dred[0][threadIdx.x][1] + dred[1][threadIdx.x][1] + dred[2][threadIdx.x][1] + dred[3][threadIdx.x][1];
    atomicAdd(&stats[threadIdx.x], S1);
    atomicAdd(&stats[64 + threadIdx.x], S2);
  }
}

// ===================== conv2_fused (r12/r13-proven): x3 = relu(bn_g(h)) + relu(bn_l(t)) inline; 64->128 conv =====================
__global__ void __launch_bounds__(256) conv2_fused(const float* __restrict__ hpre,
                                                   const float* __restrict__ tpre,
                                                   const double* __restrict__ stg,
                                                   const float* __restrict__ gg,
                                                   const float* __restrict__ bg,
                                                   const double* __restrict__ stl,
                                                   const float* __restrict__ gl,
                                                   const float* __restrict__ bel,
                                                   const float* __restrict__ w,
                                                   const float* __restrict__ bias,
                                                   float* __restrict__ outp,
                                                   double* __restrict__ stats) {
  __shared__ float scg[64], shg[64], scl[64], shl[64];
  __shared__ double red[4][8][2];
  if (threadIdx.x < 64) {
    int c = threadIdx.x;
    double mu  = stg[c] / 131072.0;
    double var = stg[64 + c] / 131072.0 - mu * mu;
    double s   = (double)gg[c] / sqrt(var + EPSI);
    scg[c] = (float)s; shg[c] = (float)((double)bg[c] - mu * s);
    double mu2  = stl[c] / 16384.0;
    double var2 = stl[64 + c] / 16384.0 - mu2 * mu2;
    double s2   = (double)gl[c] / sqrt(var2 + EPSI);
    scl[c] = (float)s2; shl[c] = (float)((double)bel[c] - mu2 * s2);
  }
  __syncthreads();
  int bz = blockIdx.x;                           // 1024 blocks
  int n  = ((bz & 7) << 8) | threadIdx.x;
  int o0 = ((bz >> 3) % 16) * 8;
  int b  = bz / 128;
  const float* hb = hpre + b * CR * NPT + n;
  const float* tb = tpre + b * CR * NPT + n;
  float a[8];
#pragma unroll
  for (int t = 0; t < 8; ++t) a[t] = bias[o0 + t];
  const float* wb = w + o0 * CR;
#pragma unroll 4
  for (int f = 0; f < CR; ++f) {
    float hv = hb[f * NPT], tv = tb[f * NPT];
    float v = fmaxf(fmaf(hv, scg[f], shg[f]), 0.f) + fmaxf(fmaf(tv, scl[f], shl[f]), 0.f);
#pragma unroll
    for (int t = 0; t < 8; ++t) a[t] += wb[t * CR + f] * v;
  }
  float* ob = outp + b * NF * NPT + n;
#pragma unroll
  for (int t = 0; t < 8; ++t) ob[(o0 + t) * NPT] = a[t];
  int lane = threadIdx.x & 63, wid = threadIdx.x >> 6;
#pragma unroll
  for (int j = 0; j < 8; ++j) {
    double s1 = (double)a[j];
    double s2 = (double)a[j] * (double)a[j];
#pragma unroll
    for (int off = 32; off; off >>= 1) { s1 += __shfl_down(s1, off); s2 += __shfl_down(s2, off); }
    if (lane == 0) { red[wid][j][0] = s1; red[wid][j][1] = s2; }
  }
  __syncthreads();
  if (threadIdx.x < 8) {
    int j = threadIdx.x;
    double S1 = red[0][j][0] + red[1][j][0] + red[2][j][0] + red[3][j][0];
    double S2 = red[0][j][1] + red[1][j][1] + red[2][j][1] + red[3][j][1];
    atomicAdd(&stats[o0 + j], S1);
    atomicAdd(&stats[NF + o0 + j], S2);
  }
}

// ===================== conv3_fused: y2 = relu(bn2(y2pre)) + feat inline; 128->256 conv + st3 =====================
// Same inline-BN fusion pattern proven in zconv / lap_fused / conv2_fused.
__global__ void __launch_bounds__(256) conv3_fused(const float* __restrict__ y2pre,
                                                   const float* __restrict__ feat,
                                                   const double* __restrict__ st2,
                                                   const float* __restrict__ g2,
                                                   const float* __restrict__ be2,
                                                   const float* __restrict__ w,
                                                   const float* __restrict__ bias,
                                                   float* __restrict__ outp,
                                                   double* __restrict__ stats) {
  __shared__ float sc[128], sh[128];
  __shared__ double red[4][8][2];
  for (int c = threadIdx.x; c < 128; c += 256) {
    double mu  = st2[c] / 16384.0;
    double var = st2[128 + c] / 16384.0 - mu * mu;
    double s   = (double)g2[c] / sqrt(var + EPSI);
    sc[c] = (float)s;
    sh[c] = (float)((double)be2[c] - mu * s);
  }
  __syncthreads();
  int bz = blockIdx.x;                           // 2048 blocks: [b(8)][og(32)][ng(8)]
  int n  = ((bz & 7) << 8) | threadIdx.x;
  int o0 = ((bz >> 3) % 32) * 8;
  int b  = bz / 256;
  const float* yb = y2pre + b * NF * NPT + n;
  const float* fb = feat  + b * NF * NPT + n;
  float a[8];
#pragma unroll
  for (int t = 0; t < 8; ++t) a[t] = bias[o0 + t];
  const float* wb = w + o0 * NF;
#pragma unroll 4
  for (int f = 0; f < NF; ++f) {
    float v = fmaxf(fmaf(yb[f * NPT], sc[f], sh[f]), 0.f) + fb[f * NPT];  // bn2+relu+feat inline
#pragma unroll
    for (int t = 0; t < 8; ++t) a[t] += wb[t * NF + f] * v;
  }
  float* ob = outp + b * 2 * NF * NPT + n;
#pragma unroll
  for (int t = 0; t < 8; ++t) ob[(o0 + t) * NPT] = a[t];
  int lane = threadIdx.x & 63, wid = threadIdx.x >> 6;
#pragma unroll
  for (int j = 0; j < 8; ++j) {
    double s1 = (double)a[j];
    double s2 = (double)a[j] * (double)a[j];
#pragma unroll
    for (int off = 32; off; off >>= 1) { s1 += __shfl_down(s1, off); s2 += __shfl_down(s2, off); }
    if (lane == 0) { red[wid][j][0] = s1; red[wid][j][1] = s2; }
  }
  __syncthreads();
  if (threadIdx.x < 8) {
    int j = threadIdx.x;
    double S1 = red[0][j][0] + red[1][j][0] + red[2][j][0] + red[3][j][0];
    double S2 = red[0][j][1] + red[1][j][1] + red[2][j][1] + red[3][j][1];
    atomicAdd(&stats[o0 + j], S1);
    atomicAdd(&stats[256 + o0 + j], S2);
  }
}

// ============================ launch (9 nodes) ============================
extern "C" void kernel_launch(void* const* d_in, const int* in_sizes, int n_in,
                              void* d_out, int out_size, void* d_ws, size_t ws_size,
                              hipStream_t stream) {
  const float* xyz  = (const float*)d_in[0];
  const float* feat = (const float*)d_in[1];
  const float* w1   = (const float*)d_in[2];
  const float* b1   = (const float*)d_in[3];
  const float* g1   = (const float*)d_in[4];
  const float* be1  = (const float*)d_in[5];
  const float* wf   = (const float*)d_in[6];
  const float* bf   = (const float*)d_in[7];
  const float* gg   = (const float*)d_in[8];
  const float* bg   = (const float*)d_in[9];
  const float* wl   = (const float*)d_in[10];
  const float* bl   = (const float*)d_in[11];
  const float* gl   = (const float*)d_in[12];
  const float* bel  = (const float*)d_in[13];
  const float* w2   = (const float*)d_in[14];
  const float* b2   = (const float*)d_in[15];
  const float* g2   = (const float*)d_in[16];
  const float* be2  = (const float*)d_in[17];
  const float* w3   = (const float*)d_in[18];
  const float* b3   = (const float*)d_in[19];
  const float* g3   = (const float*)d_in[20];
  const float* be3  = (const float*)d_in[21];
  float* out = (float*)d_out;

  // d_out scratch (all dead before conv3 writes out):
  float* x1pre = out;                      // 4MB  (pre-BN conv1 out; consumed by zconv)
  float* tpre  = out + 1048576;            // 4MB
  int*  idx16  = (int*)(out + 2097152);    // 1MB
  float* zT    = out + 2359296;            // 4MB  zT[b][n][64]
  // ws: hpre, y2pre, stats (12MB + 9KB footprint, as all passing rounds)
  float*  hpre  = (float*)d_ws;            // 4MB
  float*  y2pre = hpre + 1048576;          // 8MB (pre-BN conv2 out; bn2 applied inside conv3)
  double* stats = (double*)((char*)d_ws + (12u << 20));
  double* st0 = stats;        // 128
  double* stg = stats + 128;  // 128
  double* stl = stats + 256;  // 128
  double* st2 = stats + 384;  // 256
  double* st3 = stats + 640;  // 512

  hipMemsetAsync(stats, 0, 1152 * sizeof(double), stream);

  // 1: kNN
  knn_kernel<<<4096, 256, 0, stream>>>(xyz, idx16);
  // 2: conv1 -> x1pre + st0
  conv_stats<128, 64><<<512, 256, 0, stream>>>(feat, w1, b1, x1pre, st0);
  // 3: zconv (bn1 inline) -> zT
  zconv_kernel<<<512, 256, 0, stream>>>(x1pre, st0, g1, be1, wf, bf, zT);
  // 4: gathermax -> hpre (pre-BN max) + stg
  gathermax_kernel<<<1024, 256, 0, stream>>>(zT, idx16, hpre, stg);
  // 5: lap (BN_g inline) -> tpre + stl
  lap_fused<<<1024, 256, 0, stream>>>(hpre, idx16, wl, bl, tpre, stl, stg, gg, bg);
  // 6: conv2 (x3 inline from hpre,tpre) -> y2pre + st2
  conv2_fused<<<1024, 256, 0, stream>>>(hpre, tpre, stg, gg, bg, stl, gl, bel, w2, b2, y2pre, st2);
  // 7: conv3 (bn2 + feat residual inline) -> out + st3
  conv3_fused<<<2048, 256, 0, stream>>>(y2pre, feat, st2, g2, be2, w3, b3, out, st3);
  // 8: bn3 -> out in place
  bn_apply<256><<<1024, 256, 0, stream>>>(out, nullptr, out, st3, g3, be3, 1.0 / 16384.0);
}

// Round 15
// 249.161 us; speedup vs baseline: 1.2287x; 1.0185x over previous
//
#include <hip/hip_runtime.h>

#define NB   8
#define NPT  2048
#define NF   128
#define CR   64
#define EPSI 1e-5

// ============================ kNN (top-16, 2-D, exact f32+FMA emulation of np/jax) ============================
// PROVEN selection algebra (rounds 6..14). r15: (a) 512-thread blocks — 8 queries share the
// 24KB LDS tile -> LDS occupancy cap rises 24->32 waves/CU; (b) per-round min restructured as
// 8 group-of-4 trees + linear-over-8 (chain depth 31 -> ~9 selects). Left-to-right strict-<
// combining preserves the exact lower-index tie-break -> winner per round bit-identical.
__global__ void __launch_bounds__(512) knn_kernel(const float* __restrict__ xyz,
                                                  int* __restrict__ idx16) {
  __shared__ float px[NPT], py[NPT], sxx[NPT];
  int b = blockIdx.x >> 8;                       // 2048 blocks: 256/batch, 8 queries/block
  const float* xb = xyz + b * 3 * NPT;
  for (int i = threadIdx.x; i < NPT; i += 512) {
    float x = xb[i], y = xb[NPT + i];
    px[i] = x; py[i] = y;
    sxx[i] = __fadd_rn(__fmul_rn(x, x), __fmul_rn(y, y));
  }
  __syncthreads();
  int lane = threadIdx.x & 63, wid = threadIdx.x >> 6;   // wid in [0,8)
  int q = ((blockIdx.x & 255) << 3) | wid;
  float qx = px[q], qy = py[q], qxx = sxx[q];
  float dc[32];
#pragma unroll 4
  for (int j = 0; j < 32; ++j) {
    int m = lane + (j << 6);
    float inner_s = __fmaf_rn(qy, py[m], __fmul_rn(qx, px[m]));
    dc[j] = __fadd_rn(__fsub_rn(qxx, __fmul_rn(2.0f, inner_s)), sxx[m]);
  }
  int keep = 0;
  for (int r = 0; r < 16; ++r) {
    // grouped tree-min: 8 groups of 4 (depth 2), then linear over 8 group mins.
    float gd[8]; int gj[8];
#pragma unroll
    for (int g = 0; g < 8; ++g) {
      int base = g * 4;
      bool t01 = dc[base + 1] < dc[base];
      float d01 = t01 ? dc[base + 1] : dc[base];
      int   j01 = t01 ? base + 1 : base;
      bool t23 = dc[base + 3] < dc[base + 2];
      float d23 = t23 ? dc[base + 3] : dc[base + 2];
      int   j23 = t23 ? base + 3 : base + 2;
      bool t = d23 < d01;
      gd[g] = t ? d23 : d01;
      gj[g] = t ? j23 : j01;
    }
    float dmin = gd[0]; int jmin = gj[0];
#pragma unroll
    for (int g = 1; g < 8; ++g) {
      bool tt = gd[g] < dmin;
      dmin = tt ? gd[g] : dmin;
      jmin = tt ? gj[g] : jmin;
    }
    float hd = dmin;
    int   hm = lane + (jmin << 6);
#pragma unroll
    for (int off = 1; off < 64; off <<= 1) {
      float od = __shfl_xor(hd, off);
      int   om = __shfl_xor(hm, off);
      bool take = (od < hd) || (od == hd && om < hm);
      hd = take ? od : hd;
      hm = take ? om : hm;
    }
    if (lane == r) keep = hm;
    // hm wave-uniform; readfirstlane pins to SGPR -> scalar cmp/branch mask (r14-proven)
    unsigned rf = (unsigned)__builtin_amdgcn_readfirstlane(hm);
    bool own = (rf & 63u) == (unsigned)lane;
    int jw = (int)(rf >> 6);
#pragma unroll
    for (int j = 0; j < 32; ++j)
      if (j == jw)
        dc[j] = own ? 1e38f : dc[j];
  }
  if (lane < 16) idx16[((b * NPT + q) << 4) + lane] = keep;
}

// ===================== generic conv + atomic stats, 8 ch/block (round-7/11 proven; conv1) =====================
template<int IC, int OC>
__global__ void __launch_bounds__(256) conv_stats(const float* __restrict__ in,
                                                  const float* __restrict__ w,
                                                  const float* __restrict__ bias,
                                                  float* __restrict__ outp,
                                                  double* __restrict__ stats) {
  int bz = blockIdx.x;
  int n  = ((bz & 7) << 8) | threadIdx.x;
  int o0 = ((bz >> 3) % (OC / 8)) * 8;
  int b  = bz / (8 * (OC / 8));
  const float* inb = in + b * IC * NPT + n;
  float a[8];
#pragma unroll
  for (int t = 0; t < 8; ++t) a[t] = bias[o0 + t];
  const float* wb = w + o0 * IC;
#pragma unroll 4
  for (int f = 0; f < IC; ++f) {
    float v = inb[f * NPT];
#pragma unroll
    for (int t = 0; t < 8; ++t) a[t] += wb[t * IC + f] * v;
  }
  float* ob = outp + b * OC * NPT + n;
#pragma unroll
  for (int t = 0; t < 8; ++t) ob[(o0 + t) * NPT] = a[t];
  __shared__ double red[4][8][2];
  int lane = threadIdx.x & 63, wid = threadIdx.x >> 6;
#pragma unroll
  for (int j = 0; j < 8; ++j) {
    double s1 = (double)a[j];
    double s2 = (double)a[j] * (double)a[j];
#pragma unroll
    for (int off = 32; off; off >>= 1) { s1 += __shfl_down(s1, off); s2 += __shfl_down(s2, off); }
    if (lane == 0) { red[wid][j][0] = s1; red[wid][j][1] = s2; }
  }
  __syncthreads();
  if (threadIdx.x < 8) {
    int j = threadIdx.x;
    double S1 = red[0][j][0] + red[1][j][0] + red[2][j][0] + red[3][j][0];
    double S2 = red[0][j][1] + red[1][j][1] + red[2][j][1] + red[3][j][1];
    atomicAdd(&stats[o0 + j], S1);
    atomicAdd(&stats[OC + o0 + j], S2);
  }
}

// ===================== BN finalize + ReLU, float4 (round-7 proven; used for bn3) =====================
template<int C>
__global__ void __launch_bounds__(256) bn_apply(const float* __restrict__ pre,
                                                const float* __restrict__ addsrc,
                                                float* __restrict__ outp,
                                                const double* __restrict__ stats,
                                                const float* __restrict__ gam,
                                                const float* __restrict__ bet,
                                                double inv_cnt) {
  __shared__ float sc[C], sh[C];
  for (int c = threadIdx.x; c < C; c += 256) {
    double mu    = stats[c] * inv_cnt;
    double var   = stats[C + c] * inv_cnt - mu * mu;
    double scale = (double)gam[c] / sqrt(var + EPSI);
    sc[c] = (float)scale;
    sh[c] = (float)((double)bet[c] - mu * scale);
  }
  __syncthreads();
  const float4* pre4 = (const float4*)pre;
  const float4* add4 = (const float4*)addsrc;
  float4* out4 = (float4*)outp;
  int total4 = NB * C * (NPT / 4);
  for (int i = blockIdx.x * 256 + threadIdx.x; i < total4; i += gridDim.x * 256) {
    int c = (i >> 9) & (C - 1);
    float s = sc[c], h = sh[c];
    float4 v = pre4[i];
    v.x = fmaxf(v.x * s + h, 0.f);
    v.y = fmaxf(v.y * s + h, 0.f);
    v.z = fmaxf(v.z * s + h, 0.f);
    v.w = fmaxf(v.w * s + h, 0.f);
    if (addsrc) {
      float4 a = add4[i];
      v.x += a.x; v.y += a.y; v.z += a.z; v.w += a.w;
    }
    out4[i] = v;
  }
}

// ===================== zconv (r13-proven): z = Wf·relu(bn1(x1pre)) + bf, stored zT[n][o] =====================
__global__ void __launch_bounds__(256) zconv_kernel(const float* __restrict__ x1pre,
                                                    const double* __restrict__ st0,
                                                    const float* __restrict__ g1,
                                                    const float* __restrict__ be1,
                                                    const float* __restrict__ wf,
                                                    const float* __restrict__ bfp,
                                                    float* __restrict__ zT) {
  __shared__ float sc[64], sh[64];
  if (threadIdx.x < 64) {
    int c = threadIdx.x;
    double mu  = st0[c] / 16384.0;
    double var = st0[64 + c] / 16384.0 - mu * mu;
    double s   = (double)g1[c] / sqrt(var + EPSI);
    sc[c] = (float)s;
    sh[c] = (float)((double)be1[c] - mu * s);
  }
  __syncthreads();
  int bz = blockIdx.x;                           // 512 blocks: [b(8)][og(8)][ng(8)]
  int n  = ((bz & 7) << 8) | threadIdx.x;
  int o0 = ((bz >> 3) % 8) * 8;
  int b  = bz / 64;
  const float* inb = x1pre + b * CR * NPT + n;
  float a[8];
#pragma unroll
  for (int t = 0; t < 8; ++t) a[t] = bfp[o0 + t];
  const float* wb = wf + o0 * CR;
#pragma unroll 4
  for (int f = 0; f < CR; ++f) {
    float v = fmaxf(fmaf(inb[f * NPT], sc[f], sh[f]), 0.f);   // bn1 + relu inline
#pragma unroll
    for (int t = 0; t < 8; ++t) a[t] += wb[t * CR + f] * v;
  }
  float* zp = zT + ((b * NPT + n) << 6) + o0;    // zT[b][n][o]
  *(float4*)(zp)     = make_float4(a[0], a[1], a[2], a[3]);
  *(float4*)(zp + 4) = make_float4(a[4], a[5], a[6], a[7]);
}

// ===================== gathermax (r13-proven): h[o,n,k] = zT[src(n,k)][o]; max over k + f64 stats =====================
__global__ void __launch_bounds__(256) gathermax_kernel(const float* __restrict__ zT,
                                                        const int* __restrict__ idx16,
                                                        float* __restrict__ hmax,
                                                        double* __restrict__ stats) {
  __shared__ double dred[4][64][2];
  int lane = threadIdx.x & 63, wid = threadIdx.x >> 6;
  int wave = blockIdx.x * 4 + wid;               // 1024 blocks, 4 pts/wave
  double s1 = 0.0, s2 = 0.0;
  for (int p = 0; p < 4; ++p) {
    int pt = wave * 4 + p;
    int b = pt >> 11, n = pt & 2047;
    const float* zb = zT + ((b * NPT) << 6);
    float vals[8];
#pragma unroll
    for (int k = 0; k < 8; ++k) {
      int j = k * NPT + n;                       // torch-view scramble: idx[(j>>3), j&7]
      int src = idx16[((b * NPT + (j >> 3)) << 4) | (j & 7)];
      vals[k] = zb[(src << 6) + lane];           // coalesced: 64 lanes read 256B
    }
    float hm = vals[0];
#pragma unroll
    for (int k = 0; k < 8; ++k) {
      hm = fmaxf(hm, vals[k]);
      s1 += (double)vals[k];
      s2 += (double)vals[k] * (double)vals[k];
    }
    hmax[(b * CR + lane) * NPT + n] = hm;        // max commutes with BN+ReLU (gamma>0)
  }
  dred[wid][lane][0] = s1; dred[wid][lane][1] = s2;
  __syncthreads();
  if (threadIdx.x < 64) {
    double S1 = dred[0][threadIdx.x][0] + dred[1][threadIdx.x][0] + dred[2][threadIdx.x][0] + dred[3][threadIdx.x][0];
    double S2 = dred[0][threadIdx.x][1] + dred[1][threadIdx.x][1] + dred[2][threadIdx.x][1] + dred[3][threadIdx.x][1];
    atomicAdd(&stats[threadIdx.x], S1);
    atomicAdd(&stats[64 + threadIdx.x], S2);
  }
}

// ===================== lap_fused (rounds 8/11..14 VALIDATED): BN_g inline + mean-gather + 64x64 FC =====================
__global__ void __launch_bounds__(256) lap_fused(const float* __restrict__ hpre,
                                                 const int* __restrict__ idx16,
                                                 const float* __restrict__ wl,
                                                 const float* __restrict__ blp,
                                                 float* __restrict__ tpre,
                                                 double* __restrict__ stats,
                                                 const double* __restrict__ stg,
                                                 const float* __restrict__ gg,
                                                 const float* __restrict__ bg) {
  __shared__ float wlT[64 * 65];
  __shared__ double dred[4][64][2];
  __shared__ float vstage[4][64];
  __shared__ float scg[64], shg[64];
  for (int i = threadIdx.x; i < 64 * 64; i += 256) {
    int o = i >> 6, f = i & 63;
    wlT[f * 65 + o] = wl[i];
  }
  if (threadIdx.x < 64) {
    int c = threadIdx.x;
    double mu  = stg[c] / 131072.0;
    double var = stg[64 + c] / 131072.0 - mu * mu;
    double s   = (double)gg[c] / sqrt(var + EPSI);
    scg[c] = (float)s;
    shg[c] = (float)((double)bg[c] - mu * s);
  }
  __syncthreads();
  int lane = threadIdx.x & 63, wid = threadIdx.x >> 6;
  int g = lane >> 4, cc = lane & 15;
  float blv = blp[lane];
  double s1 = 0.0, s2 = 0.0;
  for (int p = 0; p < 4; ++p) {
    int pt = (blockIdx.x * 4 + wid) * 4 + p;
    int b = pt >> 11, n = pt & 2047;
    int ch = n >> 5;                             // gathered CHANNEL is n>>5 (torch-view scramble)
    int r0 = (n & 31) << 6;
    const float* xrow = hpre + (b * CR + ch) * NPT;
    const int* ib = idx16 + ((b * NPT + r0) << 4);
    float sgc = scg[ch], shc = shg[ch];
    float msum = 0.f;
#pragma unroll
    for (int kk = 0; kk < 16; ++kk) {
      int sidx = ib[(((kk << 2) + g) << 4) | cc];
      msum += fmaxf(fmaf(xrow[sidx], sgc, shc), 0.f);    // BN_g inline
    }
    float mval = msum * 0.0625f;
    float xraw = hpre[(b * CR + lane) * NPT + n];
    float xv = fmaxf(fmaf(xraw, scg[lane], shg[lane]), 0.f);
    vstage[wid][lane] = xv - mval;
    float acc = blv;
    for (int f = 0; f < 64; ++f)
      acc += wlT[f * 65 + lane] * vstage[wid][f];
    tpre[(b * CR + lane) * NPT + n] = acc;
    s1 += (double)acc;
    s2 += (double)acc * (double)acc;
  }
  dred[wid][lane][0] = s1; dred[wid][lane][1] = s2;
  __syncthreads();
  if (threadIdx.x < 64) {
    double S1 = dred[0][threadIdx.x][0] + dred[1][threadIdx.x][0] + dred[2][threadIdx.x][0] + dred[3][threadIdx.x][0];
    double S2 = dred[0][threadIdx.x][1] + dred[1][threadIdx.x][1] + dred[2][threadIdx.x][1] + dred[3][threadIdx.x][1];
    atomicAdd(&stats[threadIdx.x], S1);
    atomicAdd(&stats[64 + threadIdx.x], S2);
  }
}

// ===================== conv2_fused (r12/r13/r14-proven): x3 = relu(bn_g(h)) + relu(bn_l(t)) inline; 64->128 conv =====================
__global__ void __launch_bounds__(256) conv2_fused(const float* __restrict__ hpre,
                                                   const float* __restrict__ tpre,
                                                   const double* __restrict__ stg,
                                                   const float* __restrict__ gg,
                                                   const float* __restrict__ bg,
                                                   const double* __restrict__ stl,
                                                   const float* __restrict__ gl,
                                                   const float* __restrict__ bel,
                                                   const float* __restrict__ w,
                                                   const float* __restrict__ bias,
                                                   float* __restrict__ outp,
                                                   double* __restrict__ stats) {
  __shared__ float scg[64], shg[64], scl[64], shl[64];
  __shared__ double red[4][8][2];
  if (threadIdx.x < 64) {
    int c = threadIdx.x;
    double mu  = stg[c] / 131072.0;
    double var = stg[64 + c] / 131072.0 - mu * mu;
    double s   = (double)gg[c] / sqrt(var + EPSI);
    scg[c] = (float)s; shg[c] = (float)((double)bg[c] - mu * s);
    double mu2  = stl[c] / 16384.0;
    double var2 = stl[64 + c] / 16384.0 - mu2 * mu2;
    double s2   = (double)gl[c] / sqrt(var2 + EPSI);
    scl[c] = (float)s2; shl[c] = (float)((double)bel[c] - mu2 * s2);
  }
  __syncthreads();
  int bz = blockIdx.x;                           // 1024 blocks
  int n  = ((bz & 7) << 8) | threadIdx.x;
  int o0 = ((bz >> 3) % 16) * 8;
  int b  = bz / 128;
  const float* hb = hpre + b * CR * NPT + n;
  const float* tb = tpre + b * CR * NPT + n;
  float a[8];
#pragma unroll
  for (int t = 0; t < 8; ++t) a[t] = bias[o0 + t];
  const float* wb = w + o0 * CR;
#pragma unroll 4
  for (int f = 0; f < CR; ++f) {
    float hv = hb[f * NPT], tv = tb[f * NPT];
    float v = fmaxf(fmaf(hv, scg[f], shg[f]), 0.f) + fmaxf(fmaf(tv, scl[f], shl[f]), 0.f);
#pragma unroll
    for (int t = 0; t < 8; ++t) a[t] += wb[t * CR + f] * v;
  }
  float* ob = outp + b * NF * NPT + n;
#pragma unroll
  for (int t = 0; t < 8; ++t) ob[(o0 + t) * NPT] = a[t];
  int lane = threadIdx.x & 63, wid = threadIdx.x >> 6;
#pragma unroll
  for (int j = 0; j < 8; ++j) {
    double s1 = (double)a[j];
    double s2 = (double)a[j] * (double)a[j];
#pragma unroll
    for (int off = 32; off; off >>= 1) { s1 += __shfl_down(s1, off); s2 += __shfl_down(s2, off); }
    if (lane == 0) { red[wid][j][0] = s1; red[wid][j][1] = s2; }
  }
  __syncthreads();
  if (threadIdx.x < 8) {
    int j = threadIdx.x;
    double S1 = red[0][j][0] + red[1][j][0] + red[2][j][0] + red[3][j][0];
    double S2 = red[0][j][1] + red[1][j][1] + red[2][j][1] + red[3][j][1];
    atomicAdd(&stats[o0 + j], S1);
    atomicAdd(&stats[NF + o0 + j], S2);
  }
}

// ===================== conv3_fused (r14-proven): y2 = relu(bn2(y2pre)) + feat inline; 128->256 conv + st3 =====================
__global__ void __launch_bounds__(256) conv3_fused(const float* __restrict__ y2pre,
                                                   const float* __restrict__ feat,
                                                   const double* __restrict__ st2,
                                                   const float* __restrict__ g2,
                                                   const float* __restrict__ be2,
                                                   const float* __restrict__ w,
                                                   const float* __restrict__ bias,
                                                   float* __restrict__ outp,
                                                   double* __restrict__ stats) {
  __shared__ float sc[128], sh[128];
  __shared__ double red[4][8][2];
  for (int c = threadIdx.x; c < 128; c += 256) {
    double mu  = st2[c] / 16384.0;
    double var = st2[128 + c] / 16384.0 - mu * mu;
    double s   = (double)g2[c] / sqrt(var + EPSI);
    sc[c] = (float)s;
    sh[c] = (float)((double)be2[c] - mu * s);
  }
  __syncthreads();
  int bz = blockIdx.x;                           // 2048 blocks: [b(8)][og(32)][ng(8)]
  int n  = ((bz & 7) << 8) | threadIdx.x;
  int o0 = ((bz >> 3) % 32) * 8;
  int b  = bz / 256;
  const float* yb = y2pre + b * NF * NPT + n;
  const float* fb = feat  + b * NF * NPT + n;
  float a[8];
#pragma unroll
  for (int t = 0; t < 8; ++t) a[t] = bias[o0 + t];
  const float* wb = w + o0 * NF;
#pragma unroll 4
  for (int f = 0; f < NF; ++f) {
    float v = fmaxf(fmaf(yb[f * NPT], sc[f], sh[f]), 0.f) + fb[f * NPT];  // bn2+relu+feat inline
#pragma unroll
    for (int t = 0; t < 8; ++t) a[t] += wb[t * NF + f] * v;
  }
  float* ob = outp + b * 2 * NF * NPT + n;
#pragma unroll
  for (int t = 0; t < 8; ++t) ob[(o0 + t) * NPT] = a[t];
  int lane = threadIdx.x & 63, wid = threadIdx.x >> 6;
#pragma unroll
  for (int j = 0; j < 8; ++j) {
    double s1 = (double)a[j];
    double s2 = (double)a[j] * (double)a[j];
#pragma unroll
    for (int off = 32; off; off >>= 1) { s1 += __shfl_down(s1, off); s2 += __shfl_down(s2, off); }
    if (lane == 0) { red[wid][j][0] = s1; red[wid][j][1] = s2; }
  }
  __syncthreads();
  if (threadIdx.x < 8) {
    int j = threadIdx.x;
    double S1 = red[0][j][0] + red[1][j][0] + red[2][j][0] + red[3][j][0];
    double S2 = red[0][j][1] + red[1][j][1] + red[2][j][1] + red[3][j][1];
    atomicAdd(&stats[o0 + j], S1);
    atomicAdd(&stats[256 + o0 + j], S2);
  }
}

// ============================ launch (9 nodes) ============================
extern "C" void kernel_launch(void* const* d_in, const int* in_sizes, int n_in,
                              void* d_out, int out_size, void* d_ws, size_t ws_size,
                              hipStream_t stream) {
  const float* xyz  = (const float*)d_in[0];
  const float* feat = (const float*)d_in[1];
  const float* w1   = (const float*)d_in[2];
  const float* b1   = (const float*)d_in[3];
  const float* g1   = (const float*)d_in[4];
  const float* be1  = (const float*)d_in[5];
  const float* wf   = (const float*)d_in[6];
  const float* bf   = (const float*)d_in[7];
  const float* gg   = (const float*)d_in[8];
  const float* bg   = (const float*)d_in[9];
  const float* wl   = (const float*)d_in[10];
  const float* bl   = (const float*)d_in[11];
  const float* gl   = (const float*)d_in[12];
  const float* bel  = (const float*)d_in[13];
  const float* w2   = (const float*)d_in[14];
  const float* b2   = (const float*)d_in[15];
  const float* g2   = (const float*)d_in[16];
  const float* be2  = (const float*)d_in[17];
  const float* w3   = (const float*)d_in[18];
  const float* b3   = (const float*)d_in[19];
  const float* g3   = (const float*)d_in[20];
  const float* be3  = (const float*)d_in[21];
  float* out = (float*)d_out;

  // d_out scratch (all dead before conv3 writes out):
  float* x1pre = out;                      // 4MB  (pre-BN conv1 out; consumed by zconv)
  float* tpre  = out + 1048576;            // 4MB
  int*  idx16  = (int*)(out + 2097152);    // 1MB
  float* zT    = out + 2359296;            // 4MB  zT[b][n][64]
  // ws: hpre, y2pre, stats (12MB + 9KB footprint, as all passing rounds)
  float*  hpre  = (float*)d_ws;            // 4MB
  float*  y2pre = hpre + 1048576;          // 8MB (pre-BN conv2 out; bn2 applied inside conv3)
  double* stats = (double*)((char*)d_ws + (12u << 20));
  double* st0 = stats;        // 128
  double* stg = stats + 128;  // 128
  double* stl = stats + 256;  // 128
  double* st2 = stats + 384;  // 256
  double* st3 = stats + 640;  // 512

  hipMemsetAsync(stats, 0, 1152 * sizeof(double), stream);

  // 1: kNN (512-thread blocks, 8 queries/block)
  knn_kernel<<<2048, 512, 0, stream>>>(xyz, idx16);
  // 2: conv1 -> x1pre + st0
  conv_stats<128, 64><<<512, 256, 0, stream>>>(feat, w1, b1, x1pre, st0);
  // 3: zconv (bn1 inline) -> zT
  zconv_kernel<<<512, 256, 0, stream>>>(x1pre, st0, g1, be1, wf, bf, zT);
  // 4: gathermax -> hpre (pre-BN max) + stg
  gathermax_kernel<<<1024, 256, 0, stream>>>(zT, idx16, hpre, stg);
  // 5: lap (BN_g inline) -> tpre + stl
  lap_fused<<<1024, 256, 0, stream>>>(hpre, idx16, wl, bl, tpre, stl, stg, gg, bg);
  // 6: conv2 (x3 inline from hpre,tpre) -> y2pre + st2
  conv2_fused<<<1024, 256, 0, stream>>>(hpre, tpre, stg, gg, bg, stl, gl, bel, w2, b2, y2pre, st2);
  // 7: conv3 (bn2 + feat residual inline) -> out + st3
  conv3_fused<<<2048, 256, 0, stream>>>(y2pre, feat, st2, g2, be2, w3, b3, out, st3);
  // 8: bn3 -> out in place
  bn_apply<256><<<1024, 256, 0, stream>>>(out, nullptr, out, st3, g3, be3, 1.0 / 16384.0);
}